// Round 1
// 7397.581 us; speedup vs baseline: 1.1067x; 1.1067x over previous
//
#include <hip/hip_runtime.h>
#include <hip/hip_bf16.h>

// Problem constants (match reference)
constexpr int Bsz = 32;
constexpr int T   = 4096;
constexpr int P   = 64;
constexpr int IN  = 128;
constexpr int H   = 256;
constexpr long M  = (long)Bsz * T;   // 131072 rows

// ---------------------------------------------------------------------------
// K1/K3: out[m][j] = sum_c X[m][c] * W[j][c] + b1[j] + b2[j]
// ---------------------------------------------------------------------------
template <int K>
__global__ __launch_bounds__(256) void gemm_pre(
    const float* __restrict__ X, const float* __restrict__ W,
    const float* __restrict__ b1, const float* __restrict__ b2,
    float* __restrict__ out) {
  constexpr int K4 = K / 4;
  __shared__ float4 a4[16][K4];
  __shared__ float  wch[256][33];
  const int tid = threadIdx.x;
  const long m0 = (long)blockIdx.x * 16;

  const float4* X4 = (const float4*)X;
#pragma unroll
  for (int i = 0; i < (16 * K4) / 256; ++i) {
    int idx = tid + 256 * i;
    int r = idx / K4, c = idx % K4;
    a4[r][c] = X4[(m0 + r) * K4 + c];
  }

  const int j = tid;
  const float bsum = b1[j] + b2[j];
  float acc[16];
#pragma unroll
  for (int r = 0; r < 16; ++r) acc[r] = 0.f;

  const float4* W4v = (const float4*)W;
  for (int kc = 0; kc < K4; kc += 8) {
    __syncthreads();
#pragma unroll
    for (int i = 0; i < 8; ++i) {
      int idx = tid + 256 * i;
      int jr = idx >> 3, c = idx & 7;
      float4 t4 = W4v[(long)jr * K4 + kc + c];
      wch[jr][4 * c + 0] = t4.x; wch[jr][4 * c + 1] = t4.y;
      wch[jr][4 * c + 2] = t4.z; wch[jr][4 * c + 3] = t4.w;
    }
    __syncthreads();
#pragma unroll
    for (int i4 = 0; i4 < 8; ++i4) {
      float wx = wch[j][4 * i4 + 0], wy = wch[j][4 * i4 + 1];
      float wz = wch[j][4 * i4 + 2], ww = wch[j][4 * i4 + 3];
#pragma unroll
      for (int r = 0; r < 16; ++r) {
        float4 av = a4[r][kc + i4];
        acc[r] += wx * av.x + wy * av.y + wz * av.z + ww * av.w;
      }
    }
  }
#pragma unroll
  for (int r = 0; r < 16; ++r)
    out[(m0 + r) * H + j] = acc[r] + bsum;
}

// ---------------------------------------------------------------------------
// K2/K4: sequential scan. One WG (1024 thr, 16 waves) per batch element.
//
// R5 re-tile (LDS-BW fix): previous layout was (1 j x 64 k) per thread =>
// each thread ds_read 256 B of h per step => 256 KB/step/CU => 2048 cy/step
// at the 128 B/cy LDS ceiling (matched measured 2050 cy/step exactly).
// New layout: (4 j x 16 k) per thread:
//   lane = jg(0..3 | bits 0-1) x ks(0..15 | bits 2-5); wave wv owns 16 j's.
//   j = wv*16 + jg*4 + jj2, k in [ks*16, ks*16+16).
//   h read = 4x ds_read_b128 (64 B/thread) => 64 KB/step/CU (~512 cy).
//   Reduce across the 16 ks-lanes: accumulator-halving butterfly
//   xor4,xor8 (split j's), xor16, xor32 => 5 cross-lane ops (ds_swizzle x3 +
//   bpermute x1) ~160 cy/step. VALU unchanged (64 FMA/thread).
// h buffer padding: 16-word slices padded to stride 20 => the 16 distinct
//   b128 addrs (ks*20 + q*4) start at banks {0,4,...,28}+-, tiling all 32
//   banks exactly twice => free 2-way aliasing (2-way is 1.02x).
// ---------------------------------------------------------------------------
__global__ __attribute__((amdgpu_flat_work_group_size(1024, 1024),
                          amdgpu_waves_per_eu(4, 4)))
void rnn_scan(const float* __restrict__ pre, const float* __restrict__ W_hh,
              float* __restrict__ hout) {
  __shared__ __align__(16) float h_lds[2][320];   // 16 slices x (16+4 pad)

  const int tid  = threadIdx.x;
  const int lane = tid & 63;
  const int wv   = tid >> 6;           // 0..15
  const int jg   = lane & 3;           // j-group within wave
  const int ks   = lane >> 2;          // k-slice 0..15
  const int bit4 = lane & 4;
  const int bit8 = lane & 8;
  const int jj2  = ((lane >> 1) & 2) | ((lane >> 3) & 1);  // 2*b2 + b3
  const int b    = blockIdx.x;

  // Weights: rows j = wv*16 + jg*4 + r (r=0..3), cols [ks*16, ks*16+16)
  const float4* W4 = (const float4*)W_hh;
  float4 w[4][4];
#pragma unroll
  for (int r = 0; r < 4; ++r) {
    const long row = wv * 16 + jg * 4 + r;
#pragma unroll
    for (int q = 0; q < 4; ++q)
      w[r][q] = W4[row * (H / 4) + ks * 4 + q];
  }
#pragma unroll
  for (int r = 0; r < 4; ++r)
#pragma unroll
    for (int q = 0; q < 4; ++q)
      asm volatile("" : "+v"(w[r][q].x), "+v"(w[r][q].y),
                       "+v"(w[r][q].z), "+v"(w[r][q].w));

  const int  jmine  = wv * 16 + jg * 4 + jj2;   // the j this thread finishes
  const long base   = (long)b * T * H + jmine;
  const float* prej = pre + base;
  float*      houtj = hout + base;
  const int wr_word = wv * 20 + (jg * 4 + jj2); // LDS slot (lane<16 writers)

  if (tid < 2 * 320) ((float*)h_lds)[tid] = 0.f;   // zero both buffers

  float p0 = prej[0], p1 = prej[H];
  __syncthreads();

#pragma unroll 1
  for (int t = 0; t < T; ++t) {
    float p2 = (t + 2 < T) ? prej[(long)(t + 2) * H] : 0.f;  // dist-2 prefetch

    const float* hb = h_lds[t & 1] + ks * 20;
    float4 h0 = *(const float4*)(hb + 0);
    float4 h1 = *(const float4*)(hb + 4);
    float4 h2 = *(const float4*)(hb + 8);
    float4 h3 = *(const float4*)(hb + 12);

    float acc[4] = {0.f, 0.f, 0.f, 0.f};
#pragma unroll
    for (int r = 0; r < 4; ++r) {
      acc[r] += w[r][0].x * h0.x + w[r][0].y * h0.y +
                w[r][0].z * h0.z + w[r][0].w * h0.w;
      acc[r] += w[r][1].x * h1.x + w[r][1].y * h1.y +
                w[r][1].z * h1.z + w[r][1].w * h1.w;
      acc[r] += w[r][2].x * h2.x + w[r][2].y * h2.y +
                w[r][2].z * h2.z + w[r][2].w * h2.w;
      acc[r] += w[r][3].x * h3.x + w[r][3].y * h3.y +
                w[r][3].z * h3.z + w[r][3].w * h3.w;
    }
    __builtin_amdgcn_sched_barrier(0);

    // ---- accumulator-halving butterfly across the 16 ks-lanes ----
    // step 1 (xor 4): 4 accs -> 2; bit4 selects j-pair {2,3} vs {0,1}
    float t0 = bit4 ? acc[0] : acc[2];
    float t1 = bit4 ? acc[1] : acc[3];
    float r0 = __int_as_float(__builtin_amdgcn_ds_swizzle(__float_as_int(t0), 0x101F));
    float r1 = __int_as_float(__builtin_amdgcn_ds_swizzle(__float_as_int(t1), 0x101F));
    float u0 = (bit4 ? acc[2] : acc[0]) + r0;
    float u1 = (bit4 ? acc[3] : acc[1]) + r1;
    // step 2 (xor 8): 2 -> 1; bit8 selects odd vs even j of the pair
    float t2 = bit8 ? u0 : u1;
    float r2 = __int_as_float(__builtin_amdgcn_ds_swizzle(__float_as_int(t2), 0x201F));
    float s  = (bit8 ? u1 : u0) + r2;
    // steps 3,4: plain fold over remaining k-slices
    s += __int_as_float(__builtin_amdgcn_ds_swizzle(__float_as_int(s), 0x401F));
    s += __shfl_xor(s, 32, 64);

    float x = p0 + s;
    float e = __expf(2.f * x);          // e^{2x} (native v_exp path)
    float hn = 1.f - 2.f * __builtin_amdgcn_rcpf(e + 1.f);  // tanh(x)

    if (lane < 16) {                    // one writer per j (copies at lane>=16)
      h_lds[(t + 1) & 1][wr_word] = hn;
      houtj[(long)t * H] = hn;          // 64B per wave, fire-and-forget
    }
    p0 = p1; p1 = p2;
    __syncthreads();                    // single barrier per step
  }
}

// ---------------------------------------------------------------------------
// K5: out[m][p] = sigmoid( sum_j h2[m][j]*fcW[p][j] + fcb[p] )
// ---------------------------------------------------------------------------
__global__ __launch_bounds__(256) void fc_sigmoid(
    const float* __restrict__ h2, const float* __restrict__ fcW,
    const float* __restrict__ fcb, float* __restrict__ out) {
  __shared__ float h2l[16][H];
  const int tid = threadIdx.x;
  const long m0 = (long)blockIdx.x * 16;

  const float4* H4 = (const float4*)h2;
#pragma unroll
  for (int i = 0; i < 4; ++i) {
    int idx = tid + 256 * i;
    int r = idx >> 6, c4 = idx & 63;
    *(float4*)&h2l[r][4 * c4] = H4[(m0 + r) * (H / 4) + c4];
  }
  __syncthreads();

  const int p = tid & 63, rq = tid >> 6;
  const float4* W4 = (const float4*)fcW;
  float acc[4] = {0.f, 0.f, 0.f, 0.f};
#pragma unroll 8
  for (int c4 = 0; c4 < H / 4; ++c4) {
    float4 wv = W4[(long)p * (H / 4) + c4];
#pragma unroll
    for (int k = 0; k < 4; ++k) {
      float4 av = *(const float4*)&h2l[rq * 4 + k][4 * c4];
      acc[k] += wv.x * av.x + wv.y * av.y + wv.z * av.z + wv.w * av.w;
    }
  }
  const float bb = fcb[p];
#pragma unroll
  for (int k = 0; k < 4; ++k) {
    float x = acc[k] + bb;
    out[(m0 + rq * 4 + k) * P + p] = 1.f / (1.f + __expf(-x));
  }
}

// ---------------------------------------------------------------------------
extern "C" void kernel_launch(void* const* d_in, const int* in_sizes, int n_in,
                              void* d_out, int out_size, void* d_ws, size_t ws_size,
                              hipStream_t stream) {
  const float* input = (const float*)d_in[0];
  const float* W_ih0 = (const float*)d_in[1];
  const float* W_hh0 = (const float*)d_in[2];
  const float* b_ih0 = (const float*)d_in[3];
  const float* b_hh0 = (const float*)d_in[4];
  const float* W_ih1 = (const float*)d_in[5];
  const float* W_hh1 = (const float*)d_in[6];
  const float* b_ih1 = (const float*)d_in[7];
  const float* b_hh1 = (const float*)d_in[8];
  const float* fc_W  = (const float*)d_in[9];
  const float* fc_b  = (const float*)d_in[10];
  float* out = (float*)d_out;

  float* bufA = (float*)d_ws;                 // pre0 -> pre1
  float* bufB = bufA + (size_t)M * H;         // h1 -> h2

  gemm_pre<IN><<<(int)(M / 16), 256, 0, stream>>>(input, W_ih0, b_ih0, b_hh0, bufA);
  rnn_scan<<<Bsz, 1024, 0, stream>>>(bufA, W_hh0, bufB);
  gemm_pre<H><<<(int)(M / 16), 256, 0, stream>>>(bufB, W_ih1, b_ih1, b_hh1, bufA);
  rnn_scan<<<Bsz, 1024, 0, stream>>>(bufA, W_hh1, bufB);
  fc_sigmoid<<<(int)(M / 16), 256, 0, stream>>>(bufB, fc_W, fc_b, out);
}